// Round 1
// baseline (645.938 us; speedup 1.0000x reference)
//
#include <hip/hip_runtime.h>
#include <hip/hip_bf16.h>
#include <stdint.h>

using bf16 = __hip_bfloat16;
typedef __attribute__((ext_vector_type(8))) short short8;
typedef __attribute__((ext_vector_type(4))) float floatx4;

#define DEVINL __device__ __forceinline__

constexpr int K_DIM = 4096;
constexpr int N_DIM = 4096;
constexpr int M_DIM = 8192;   // B * S = 2 * 4096

// ---- async global->LDS, 16B per lane; LDS dest = wave-uniform base + lane*16
DEVINL void gload_lds16(const void* g, void* l) {
  __builtin_amdgcn_global_load_lds((const __attribute__((address_space(1))) void*)g,
                                   (__attribute__((address_space(3))) void*)l,
                                   16, 0, 0);
}

// =====================================================================
// Prep (fused): blocks [0, 8192) = GPTQ int4 dequant -> bf16 W^T [N][K]
//               blocks [8192, 24576) = A fp32 -> bf16
// Both memory-bound; fusing lets them share CUs instead of serializing.
// =====================================================================
__global__ __launch_bounds__(256) void k_prep(const int* __restrict__ qw,
                                              const float* __restrict__ scales,
                                              const int* __restrict__ qz,
                                              bf16* __restrict__ wt,
                                              const float* __restrict__ a,
                                              bf16* __restrict__ ao) {
  if (blockIdx.x < 64 * 128) {
    // ---- dequant (verified): coalesced read, LDS transpose, 128B-run writes
    __shared__ __align__(16) uint4 lds[32 * 8];   // [n_local][kp_local^swz]
    const int b = blockIdx.x;
    const int kp0 = (b & 63) * 8;
    const int n0  = (b >> 6) * 32;
    const int t = threadIdx.x;
    const int n_l = t & 31, kp_l = t >> 5;
    const int n = n0 + n_l, kp = kp0 + kp_l;

    int q = qw[kp * N_DIM + n];
    int g = kp0 >> 4;                             // uniform (kp0 % 8 == 0)
    float s = scales[g * N_DIM + n];
    int zword = qz[g * (N_DIM / 8) + (n >> 3)];
    float z = (float)((zword >> ((n & 7) * 4)) & 0xF);
    float nzs = -z * s;
    bf16 h[8];
#pragma unroll
    for (int i = 0; i < 8; ++i) {
      float w = fmaf((float)((q >> (4 * i)) & 0xF), s, nzs);
      h[i] = __float2bfloat16(w);
    }
    lds[n_l * 8 + (kp_l ^ (n_l & 7))] = *(const uint4*)h;
    __syncthreads();
    const int n_o = t >> 3, kp_o = t & 7;
    uint4 v = lds[n_o * 8 + (kp_o ^ (n_o & 7))];
    ((uint4*)wt)[(size_t)(n0 + n_o) * (K_DIM / 8) + kp0 + kp_o] = v;
  } else {
    // ---- A convert: 8 fp32 -> 8 bf16 per thread
    int t = (blockIdx.x - 64 * 128) * 256 + threadIdx.x;
    const float4* a4 = (const float4*)a;
    float4 v0 = a4[2 * t], v1 = a4[2 * t + 1];
    bf16 h[8];
    h[0] = __float2bfloat16(v0.x); h[1] = __float2bfloat16(v0.y);
    h[2] = __float2bfloat16(v0.z); h[3] = __float2bfloat16(v0.w);
    h[4] = __float2bfloat16(v1.x); h[5] = __float2bfloat16(v1.y);
    h[6] = __float2bfloat16(v1.z); h[7] = __float2bfloat16(v1.w);
    ((uint4*)ao)[t] = *(const uint4*)h;
  }
}

// =====================================================================
// Fallback GEMM (old verified 128x128, fp32-A path) — used only if the
// workspace can't hold the bf16 A copy.
// =====================================================================
constexpr int BM = 128, BN = 128, BK = 64;
constexpr int NBLK_N = N_DIM / BN;
constexpr int NBLK_M = M_DIM / BM;

template <bool A_IS_BF16>
__global__ __launch_bounds__(256, 2) void k_gemm(const void* __restrict__ a_ptr,
                                                 const bf16* __restrict__ wt,
                                                 const float* __restrict__ bias,
                                                 const float* __restrict__ residual,
                                                 float* __restrict__ out) {
  __shared__ __align__(16) bf16 As[BM * BK];
  __shared__ __align__(16) bf16 Bs[BN * BK];

  const int tid  = threadIdx.x;
  const int lane = tid & 63;
  const int wave = tid >> 6;
  const int wr = wave >> 1, wc = wave & 1;
  const int quad = lane >> 4, lq = lane & 15;

  const int xcd = blockIdx.x & 7;
  const int idx = blockIdx.x >> 3;
  const int bn = xcd * 4 + (idx & 3);
  const int bm = idx >> 2;
  const int m0 = bm * BM, n0 = bn * BN;

  floatx4 acc[4][4] = {};

  const int st_r8 = lane >> 3;
  const int st_ce = ((lane & 7) ^ (st_r8 & 7)) * 8;
  const int rd_x = lq & 7;

  const bf16*  a_bf = (const bf16*)a_ptr;
  const float* a_f  = (const float*)a_ptr;

  for (int k0 = 0; k0 < K_DIM; k0 += BK) {
    __syncthreads();
#pragma unroll
    for (int j = 0; j < 4; ++j) {
      int g = wave + j * 4;
      const bf16* gp = wt + (size_t)(n0 + g * 8 + st_r8) * K_DIM + k0 + st_ce;
      gload_lds16(gp, &Bs[g * 512]);
    }
    if (A_IS_BF16) {
#pragma unroll
      for (int j = 0; j < 4; ++j) {
        int g = wave + j * 4;
        const bf16* gp = a_bf + (size_t)(m0 + g * 8 + st_r8) * K_DIM + k0 + st_ce;
        gload_lds16(gp, &As[g * 512]);
      }
    } else {
      int row = tid >> 1, half = tid & 1;
      int rx = row & 7;
      const float* srcf = a_f + (size_t)(m0 + row) * K_DIM + k0 + half * 32;
#pragma unroll
      for (int cc = 0; cc < 4; ++cc) {
        int logc = half * 4 + cc;
        float4 v0 = ((const float4*)srcf)[cc * 2];
        float4 v1 = ((const float4*)srcf)[cc * 2 + 1];
        bf16 h[8];
        h[0] = __float2bfloat16(v0.x); h[1] = __float2bfloat16(v0.y);
        h[2] = __float2bfloat16(v0.z); h[3] = __float2bfloat16(v0.w);
        h[4] = __float2bfloat16(v1.x); h[5] = __float2bfloat16(v1.y);
        h[6] = __float2bfloat16(v1.z); h[7] = __float2bfloat16(v1.w);
        *(uint4*)&As[row * BK + ((logc ^ rx) * 8)] = *(const uint4*)h;
      }
    }
    __syncthreads();

#pragma unroll
    for (int s = 0; s < 2; ++s) {
      short8 afr[4], bfr[4];
#pragma unroll
      for (int mi = 0; mi < 4; ++mi)
        afr[mi] = *(const short8*)&As[(wr * 64 + mi * 16 + lq) * BK +
                                      (((s * 4 + quad) ^ rd_x) * 8)];
#pragma unroll
      for (int ni = 0; ni < 4; ++ni)
        bfr[ni] = *(const short8*)&Bs[(wc * 64 + ni * 16 + lq) * BK +
                                      (((s * 4 + quad) ^ rd_x) * 8)];
#pragma unroll
      for (int mi = 0; mi < 4; ++mi)
#pragma unroll
        for (int ni = 0; ni < 4; ++ni)
          acc[mi][ni] = __builtin_amdgcn_mfma_f32_16x16x32_bf16(afr[mi], bfr[ni],
                                                                acc[mi][ni], 0, 0, 0);
    }
  }

#pragma unroll
  for (int ni = 0; ni < 4; ++ni) {
    int col = n0 + wc * 64 + ni * 16 + lq;
    float bv = bias[col];
#pragma unroll
    for (int mi = 0; mi < 4; ++mi) {
      int rbase = m0 + wr * 64 + mi * 16 + quad * 4;
#pragma unroll
      for (int r = 0; r < 4; ++r) {
        size_t idxo = (size_t)(rbase + r) * N_DIM + col;
        out[idxo] = acc[mi][ni][r] + bv + residual[idxo];
      }
    }
  }
}

// =====================================================================
// Main GEMM: 256x256 tile, BK=64, 8 waves (2Mx4N), 8-phase schedule with
// counted vmcnt (learn_hip m201 template, adapted).
//
// Staging rotation (tile t, buffers by K-tile parity):
//   phase 0 (qm=0,qn=0): reads A-lo,B-lo | stage A-hi(t+1) -> buf[t+1]
//   phase 1 (qm=0,qn=1): reads A-lo,B-hi | stage B-hi(t+1) -> buf[t+1]
//   phase 2 (qm=1,qn=0): reads A-hi,B-lo | stage A-lo(t+2) -> buf[t]   (A-lo dead after p1)
//   phase 3 (qm=1,qn=1): reads A-hi,B-hi | stage B-lo(t+2) -> buf[t]   (B-lo dead after p2)
//   then s_waitcnt vmcnt(4): drains everything tile t+1 needs, leaves
//   A-lo(t+2)/B-lo(t+2) (4 loads/wave) in flight across all of tile t+1.
// Raw s_barrier everywhere (never __syncthreads -> no vmcnt(0) drain).
// Per-wave C: rows {qm*128 + wm*64 + [0,64)}, cols {qn*128 + wn*32 + [0,32)}.
// LDS swizzle identical to the verified fallback (0 bank conflicts).
// =====================================================================
constexpr int TBK = 64;
constexpr int TNT = K_DIM / TBK;   // 64 K-tiles

#define VM4 asm volatile("s_waitcnt vmcnt(4)" ::: "memory")
#define VM0 asm volatile("s_waitcnt vmcnt(0)" ::: "memory")
#define VMN

#define STAGE_A(buf, half, kt) {                                                   \
    const bf16* g0_ = A + (size_t)(m0 + (half) * 128 + wave * 16 + st_r) * K_DIM   \
                        + (kt) * TBK + st_c;                                       \
    gload_lds16(g0_,             &As[buf][(half) * 128 + wave * 16    ][0]);       \
    gload_lds16(g0_ + 8 * K_DIM, &As[buf][(half) * 128 + wave * 16 + 8][0]);       \
  }

#define STAGE_B(buf, half, kt) {                                                   \
    const bf16* g1_ = Bw + (size_t)(n0 + (half) * 128 + wave * 16 + st_r) * K_DIM  \
                        + (kt) * TBK + st_c;                                       \
    gload_lds16(g1_,             &Bs[buf][(half) * 128 + wave * 16    ][0]);       \
    gload_lds16(g1_ + 8 * K_DIM, &Bs[buf][(half) * 128 + wave * 16 + 8][0]);       \
  }

#define PHASE(cur, qm, qn, STG)                                                    \
  {                                                                                \
    short8 afr[4][2], bfr[2][2];                                                   \
    _Pragma("unroll") for (int mi = 0; mi < 4; ++mi) {                             \
      _Pragma("unroll") for (int s = 0; s < 2; ++s)                                \
        afr[mi][s] = *(const short8*)&As[cur][(qm) * 128 + wm * 64 + mi * 16 + l15]\
                                        [rdc[s]];                                  \
    }                                                                              \
    _Pragma("unroll") for (int ni = 0; ni < 2; ++ni) {                             \
      _Pragma("unroll") for (int s = 0; s < 2; ++s)                                \
        bfr[ni][s] = *(const short8*)&Bs[cur][(qn) * 128 + wn * 32 + ni * 16 + l15]\
                                        [rdc[s]];                                  \
    }                                                                              \
    STG;                                                                           \
    __builtin_amdgcn_sched_barrier(0);                                             \
    __builtin_amdgcn_s_barrier();                                                  \
    __builtin_amdgcn_s_setprio(1);                                                 \
    _Pragma("unroll") for (int mi = 0; mi < 4; ++mi) {                             \
      _Pragma("unroll") for (int ni = 0; ni < 2; ++ni) {                           \
        acc[qm][qn][mi][ni] = __builtin_amdgcn_mfma_f32_16x16x32_bf16(             \
            afr[mi][0], bfr[ni][0], acc[qm][qn][mi][ni], 0, 0, 0);                 \
        acc[qm][qn][mi][ni] = __builtin_amdgcn_mfma_f32_16x16x32_bf16(             \
            afr[mi][1], bfr[ni][1], acc[qm][qn][mi][ni], 0, 0, 0);                 \
      }                                                                            \
    }                                                                              \
    __builtin_amdgcn_s_setprio(0);                                                 \
    __builtin_amdgcn_sched_barrier(0);                                             \
  }

#define TILE(cur, SHI, SLO, thi, tlo, VMW)                                         \
  PHASE(cur, 0, 0, if (SHI) STAGE_A((cur) ^ 1, 1, thi))                            \
  __builtin_amdgcn_s_barrier();                                                    \
  PHASE(cur, 0, 1, if (SHI) STAGE_B((cur) ^ 1, 1, thi))                            \
  __builtin_amdgcn_s_barrier();                                                    \
  PHASE(cur, 1, 0, if (SLO) STAGE_A((cur), 0, tlo))                                \
  __builtin_amdgcn_s_barrier();                                                    \
  PHASE(cur, 1, 1, if (SLO) STAGE_B((cur), 0, tlo))                                \
  VMW;                                                                             \
  __builtin_amdgcn_s_barrier();

__global__ __launch_bounds__(512, 2) void k_gemm8(const bf16* __restrict__ A,
                                                  const bf16* __restrict__ Bw,
                                                  const float* __restrict__ bias,
                                                  const float* __restrict__ residual,
                                                  float* __restrict__ out) {
  __shared__ __align__(16) bf16 As[2][256][TBK];   // 64 KB
  __shared__ __align__(16) bf16 Bs[2][256][TBK];   // 64 KB

  const int tid  = threadIdx.x;
  const int lane = tid & 63;
  const int wave = tid >> 6;          // 0..7
  const int wm = wave >> 2;           // 0..1
  const int wn = wave & 3;            // 0..3
  const int quad = lane >> 4, l15 = lane & 15;

  // bijective XCD swizzle (512 % 8 == 0): each XCD owns 2 bn columns (4 MiB wt
  // panel in its L2); consecutive locals pair over bn so 2 blocks share A-tiles.
  const int wgid = (blockIdx.x & 7) * 64 + (blockIdx.x >> 3);
  const int bn = (wgid >> 6) * 2 + (wgid & 1);
  const int bm = (wgid & 63) >> 1;
  const int m0 = bm * 256, n0 = bn * 256;

  // staging: instr j covers 8 rows x 128 B; lane -> row (l>>3), phys chunk l&7;
  // source fetches logical chunk (l&7)^(row&7) so LDS holds the XOR swizzle.
  const int st_r = lane >> 3;
  const int st_c = ((lane & 7) ^ st_r) * 8;

  // fragment read: logical chunk (s*4+quad) of row r -> phys ^= (r&7) = l15&7
  const int rdc[2] = { ((quad)     ^ (l15 & 7)) * 8,
                       ((4 + quad) ^ (l15 & 7)) * 8 };

  floatx4 acc[2][2][4][2] = {};   // [qm][qn][mi][ni] -> 128 VGPR

  // ---- prologue: tile0 complete + A-lo/B-lo of tile1 in flight
  STAGE_A(0, 0, 0)
  STAGE_B(0, 0, 0)
  STAGE_A(0, 1, 0)
  STAGE_B(0, 1, 0)
  STAGE_A(1, 0, 1)
  STAGE_B(1, 0, 1)
  VM4;                               // drain tile0's 8 loads, leave 4 in flight
  __builtin_amdgcn_s_barrier();

#pragma unroll 1
  for (int t = 0; t < TNT - 2; t += 2) {
    TILE(0, true, true, t + 1, t + 2, VM4)
    TILE(1, true, true, t + 2, t + 3, VM4)
  }
  TILE(0, true, false, TNT - 1, 0, VM0)   // t = 62: stage hi(63); drain all
  TILE(1, false, false, 0, 0, VMN)        // t = 63: compute only

  // ---- epilogue: out = acc + bias + residual (C/D: col=l15, row=quad*4+r)
#pragma unroll
  for (int qn = 0; qn < 2; ++qn)
#pragma unroll
    for (int ni = 0; ni < 2; ++ni) {
      int col = n0 + qn * 128 + wn * 32 + ni * 16 + l15;
      float bv = bias[col];
#pragma unroll
      for (int qm = 0; qm < 2; ++qm)
#pragma unroll
        for (int mi = 0; mi < 4; ++mi) {
          int rbase = m0 + qm * 128 + wm * 64 + mi * 16 + quad * 4;
#pragma unroll
          for (int r = 0; r < 4; ++r) {
            size_t o = (size_t)(rbase + r) * N_DIM + col;
            out[o] = acc[qm][qn][mi][ni][r] + bv + residual[o];
          }
        }
    }
}

extern "C" void kernel_launch(void* const* d_in, const int* in_sizes, int n_in,
                              void* d_out, int out_size, void* d_ws, size_t ws_size,
                              hipStream_t stream) {
  const float* input    = (const float*)d_in[0];
  const float* residual = (const float*)d_in[1];
  const int*   qweight  = (const int*)d_in[2];
  const float* scales   = (const float*)d_in[3];
  const int*   qzeros   = (const int*)d_in[4];
  const float* bias     = (const float*)d_in[5];
  float* out = (float*)d_out;

  const size_t wt_bytes = (size_t)N_DIM * K_DIM * sizeof(bf16);   // 32 MiB
  const size_t a_bytes  = (size_t)M_DIM * K_DIM * sizeof(bf16);   // 64 MiB

  bf16* wt = (bf16*)d_ws;

  if (ws_size >= wt_bytes + a_bytes) {
    bf16* a_bf = (bf16*)((char*)d_ws + wt_bytes);
    k_prep<<<64 * 128 + (M_DIM * K_DIM / 8) / 256, 256, 0, stream>>>(
        qweight, scales, qzeros, wt, input, a_bf);
    k_gemm8<<<(M_DIM / 256) * (N_DIM / 256), 512, 0, stream>>>(
        a_bf, wt, bias, residual, out);
  } else {
    k_prep<<<64 * 128, 256, 0, stream>>>(qweight, scales, qzeros, wt, input, nullptr);
    k_gemm<false><<<NBLK_M * NBLK_N, 256, 0, stream>>>(input, wt, bias, residual, out);
  }
}

// Round 2
// 598.212 us; speedup vs baseline: 1.0798x; 1.0798x over previous
//
#include <hip/hip_runtime.h>
#include <hip/hip_bf16.h>
#include <stdint.h>

using bf16 = __hip_bfloat16;
typedef __attribute__((ext_vector_type(8))) short short8;
typedef __attribute__((ext_vector_type(4))) float floatx4;

#define DEVINL __device__ __forceinline__

constexpr int K_DIM = 4096;
constexpr int N_DIM = 4096;
constexpr int M_DIM = 8192;   // B * S = 2 * 4096

// ---- async global->LDS, 16B per lane; LDS dest = wave-uniform base + lane*16
DEVINL void gload_lds16(const void* g, void* l) {
  __builtin_amdgcn_global_load_lds((const __attribute__((address_space(1))) void*)g,
                                   (__attribute__((address_space(3))) void*)l,
                                   16, 0, 0);
}

// =====================================================================
// Prep (fused): blocks [0, 8192) = GPTQ int4 dequant -> bf16 W^T [N][K]
//               blocks [8192, 24576) = A fp32 -> bf16
// =====================================================================
__global__ __launch_bounds__(256) void k_prep(const int* __restrict__ qw,
                                              const float* __restrict__ scales,
                                              const int* __restrict__ qz,
                                              bf16* __restrict__ wt,
                                              const float* __restrict__ a,
                                              bf16* __restrict__ ao) {
  if (blockIdx.x < 64 * 128) {
    __shared__ __align__(16) uint4 lds[32 * 8];
    const int b = blockIdx.x;
    const int kp0 = (b & 63) * 8;
    const int n0  = (b >> 6) * 32;
    const int t = threadIdx.x;
    const int n_l = t & 31, kp_l = t >> 5;
    const int n = n0 + n_l, kp = kp0 + kp_l;

    int q = qw[kp * N_DIM + n];
    int g = kp0 >> 4;
    float s = scales[g * N_DIM + n];
    int zword = qz[g * (N_DIM / 8) + (n >> 3)];
    float z = (float)((zword >> ((n & 7) * 4)) & 0xF);
    float nzs = -z * s;
    bf16 h[8];
#pragma unroll
    for (int i = 0; i < 8; ++i) {
      float w = fmaf((float)((q >> (4 * i)) & 0xF), s, nzs);
      h[i] = __float2bfloat16(w);
    }
    lds[n_l * 8 + (kp_l ^ (n_l & 7))] = *(const uint4*)h;
    __syncthreads();
    const int n_o = t >> 3, kp_o = t & 7;
    uint4 v = lds[n_o * 8 + (kp_o ^ (n_o & 7))];
    ((uint4*)wt)[(size_t)(n0 + n_o) * (K_DIM / 8) + kp0 + kp_o] = v;
  } else {
    int t = (blockIdx.x - 64 * 128) * 256 + threadIdx.x;
    const float4* a4 = (const float4*)a;
    float4 v0 = a4[2 * t], v1 = a4[2 * t + 1];
    bf16 h[8];
    h[0] = __float2bfloat16(v0.x); h[1] = __float2bfloat16(v0.y);
    h[2] = __float2bfloat16(v0.z); h[3] = __float2bfloat16(v0.w);
    h[4] = __float2bfloat16(v1.x); h[5] = __float2bfloat16(v1.y);
    h[6] = __float2bfloat16(v1.z); h[7] = __float2bfloat16(v1.w);
    ((uint4*)ao)[t] = *(const uint4*)h;
  }
}

// =====================================================================
// Fallback GEMM (verified 128x128, fp32-A path) — small-workspace only.
// =====================================================================
constexpr int BM = 128, BN = 128, BK = 64;
constexpr int NBLK_N = N_DIM / BN;
constexpr int NBLK_M = M_DIM / BM;

template <bool A_IS_BF16>
__global__ __launch_bounds__(256, 2) void k_gemm(const void* __restrict__ a_ptr,
                                                 const bf16* __restrict__ wt,
                                                 const float* __restrict__ bias,
                                                 const float* __restrict__ residual,
                                                 float* __restrict__ out) {
  __shared__ __align__(16) bf16 As[BM * BK];
  __shared__ __align__(16) bf16 Bs[BN * BK];

  const int tid  = threadIdx.x;
  const int lane = tid & 63;
  const int wave = tid >> 6;
  const int wr = wave >> 1, wc = wave & 1;
  const int quad = lane >> 4, lq = lane & 15;

  const int xcd = blockIdx.x & 7;
  const int idx = blockIdx.x >> 3;
  const int bn = xcd * 4 + (idx & 3);
  const int bm = idx >> 2;
  const int m0 = bm * BM, n0 = bn * BN;

  floatx4 acc[4][4] = {};

  const int st_r8 = lane >> 3;
  const int st_ce = ((lane & 7) ^ (st_r8 & 7)) * 8;
  const int rd_x = lq & 7;

  const bf16*  a_bf = (const bf16*)a_ptr;
  const float* a_f  = (const float*)a_ptr;

  for (int k0 = 0; k0 < K_DIM; k0 += BK) {
    __syncthreads();
#pragma unroll
    for (int j = 0; j < 4; ++j) {
      int g = wave + j * 4;
      const bf16* gp = wt + (size_t)(n0 + g * 8 + st_r8) * K_DIM + k0 + st_ce;
      gload_lds16(gp, &Bs[g * 512]);
    }
    if (A_IS_BF16) {
#pragma unroll
      for (int j = 0; j < 4; ++j) {
        int g = wave + j * 4;
        const bf16* gp = a_bf + (size_t)(m0 + g * 8 + st_r8) * K_DIM + k0 + st_ce;
        gload_lds16(gp, &As[g * 512]);
      }
    } else {
      int row = tid >> 1, half = tid & 1;
      int rx = row & 7;
      const float* srcf = a_f + (size_t)(m0 + row) * K_DIM + k0 + half * 32;
#pragma unroll
      for (int cc = 0; cc < 4; ++cc) {
        int logc = half * 4 + cc;
        float4 v0 = ((const float4*)srcf)[cc * 2];
        float4 v1 = ((const float4*)srcf)[cc * 2 + 1];
        bf16 h[8];
        h[0] = __float2bfloat16(v0.x); h[1] = __float2bfloat16(v0.y);
        h[2] = __float2bfloat16(v0.z); h[3] = __float2bfloat16(v0.w);
        h[4] = __float2bfloat16(v1.x); h[5] = __float2bfloat16(v1.y);
        h[6] = __float2bfloat16(v1.z); h[7] = __float2bfloat16(v1.w);
        *(uint4*)&As[row * BK + ((logc ^ rx) * 8)] = *(const uint4*)h;
      }
    }
    __syncthreads();

#pragma unroll
    for (int s = 0; s < 2; ++s) {
      short8 afr[4], bfr[4];
#pragma unroll
      for (int mi = 0; mi < 4; ++mi)
        afr[mi] = *(const short8*)&As[(wr * 64 + mi * 16 + lq) * BK +
                                      (((s * 4 + quad) ^ rd_x) * 8)];
#pragma unroll
      for (int ni = 0; ni < 4; ++ni)
        bfr[ni] = *(const short8*)&Bs[(wc * 64 + ni * 16 + lq) * BK +
                                      (((s * 4 + quad) ^ rd_x) * 8)];
#pragma unroll
      for (int mi = 0; mi < 4; ++mi)
#pragma unroll
        for (int ni = 0; ni < 4; ++ni)
          acc[mi][ni] = __builtin_amdgcn_mfma_f32_16x16x32_bf16(afr[mi], bfr[ni],
                                                                acc[mi][ni], 0, 0, 0);
    }
  }

#pragma unroll
  for (int ni = 0; ni < 4; ++ni) {
    int col = n0 + wc * 64 + ni * 16 + lq;
    float bv = bias[col];
#pragma unroll
    for (int mi = 0; mi < 4; ++mi) {
      int rbase = m0 + wr * 64 + mi * 16 + quad * 4;
#pragma unroll
      for (int r = 0; r < 4; ++r) {
        size_t idxo = (size_t)(rbase + r) * N_DIM + col;
        out[idxo] = acc[mi][ni][r] + bv + residual[idxo];
      }
    }
  }
}

// =====================================================================
// Main GEMM: 256x256 tile, BK=64, 8 waves (2Mx4N).
// TWO big phases per K-tile (phase = A-half qm); B-frags loaded ONCE per
// tile (held in regs across both phases) -> 24 ds_read_b128/wave/tile
// (vs 48 in the 4-quadrant scheme) < MFMA-pipe time: MFMA-bound.
// ONE barrier per phase (stages only ever write the non-compute buffer,
// so no intra-tile read/write hazard; cross-tile protected by vmcnt+bar).
//
// Per-wave vmem queue, steady state (2 loads per STAGE):
//   stages during tile t-1: p0: Alo(t),Blo(t),Bhi(t) ; p1: Ahi(t)
//   end of p0 of t: [Ahi(t)·2 | Alo,Blo,Bhi(t+1)·6] -> vmcnt(6)
//   end of p1 of t: [lo+Bhi(t+1)·6 | Ahi(t+1)·2]    -> vmcnt(2)
// Every half-tile has >= 1 full phase (~1200+ cyc) of latency cover.
// Tail: tile 63 stages nothing, waits vmcnt(0) before its p1.
// =====================================================================
constexpr int TBK = 64;
constexpr int TNT = K_DIM / TBK;   // 64

#define SB0  __builtin_amdgcn_sched_barrier(0)
#define SBAR __builtin_amdgcn_s_barrier()
#define VMW(n) asm volatile("s_waitcnt vmcnt(" #n ")" ::: "memory")

#define STAGE_A(buf, half, p) {                                                    \
    gload_lds16((p) + (size_t)(half) * 128 * K_DIM,                                \
                &As[buf][(half) * 128 + wave * 16][0]);                            \
    gload_lds16((p) + (size_t)(half) * 128 * K_DIM + 8 * K_DIM,                    \
                &As[buf][(half) * 128 + wave * 16 + 8][0]);                        \
  }

#define STAGE_B(buf, half, p) {                                                    \
    gload_lds16((p) + (size_t)(half) * 128 * K_DIM,                                \
                &Bs[buf][(half) * 128 + wave * 16][0]);                            \
    gload_lds16((p) + (size_t)(half) * 128 * K_DIM + 8 * K_DIM,                    \
                &Bs[buf][(half) * 128 + wave * 16 + 8][0]);                        \
  }

#define TILE(c, DO_STAGE, LAST)                                                    \
  {                                                                                \
    /* ---------- phase 0: qm = 0 ---------- */                                    \
    short8 bfr[2][2][2], a0[4][2];                                                 \
    _Pragma("unroll") for (int qn = 0; qn < 2; ++qn)                               \
      _Pragma("unroll") for (int ni = 0; ni < 2; ++ni)                             \
        _Pragma("unroll") for (int s = 0; s < 2; ++s)                              \
          bfr[qn][ni][s] = *(const short8*)                                        \
              &Bs[c][qn * 128 + wn * 32 + ni * 16 + l15][rdc[s]];                  \
    _Pragma("unroll") for (int mi = 0; mi < 4; ++mi)                               \
      _Pragma("unroll") for (int s = 0; s < 2; ++s)                                \
        a0[mi][s] = *(const short8*)&As[c][wm * 64 + mi * 16 + l15][rdc[s]];       \
    if (DO_STAGE) {                                                                \
      STAGE_A((c) ^ 1, 0, aP)                                                      \
      STAGE_B((c) ^ 1, 0, bP)                                                      \
      STAGE_B((c) ^ 1, 1, bP)                                                      \
    }                                                                              \
    SB0;                                                                           \
    __builtin_amdgcn_s_setprio(1);                                                 \
    _Pragma("unroll") for (int s = 0; s < 2; ++s)                                  \
      _Pragma("unroll") for (int mi = 0; mi < 4; ++mi)                             \
        _Pragma("unroll") for (int qn = 0; qn < 2; ++qn)                           \
          _Pragma("unroll") for (int ni = 0; ni < 2; ++ni)                         \
            acc[0][qn][mi][ni] = __builtin_amdgcn_mfma_f32_16x16x32_bf16(          \
                a0[mi][s], bfr[qn][ni][s], acc[0][qn][mi][ni], 0, 0, 0);           \
    __builtin_amdgcn_s_setprio(0);                                                 \
    SB0;                                                                           \
    if (LAST) { VMW(0); } else { VMW(6); }                                         \
    SBAR;                                                                          \
    /* ---------- phase 1: qm = 1 ---------- */                                    \
    short8 a1[4][2];                                                               \
    _Pragma("unroll") for (int mi = 0; mi < 4; ++mi)                               \
      _Pragma("unroll") for (int s = 0; s < 2; ++s)                                \
        a1[mi][s] = *(const short8*)&As[c][128 + wm * 64 + mi * 16 + l15][rdc[s]]; \
    if (DO_STAGE) {                                                                \
      STAGE_A((c) ^ 1, 1, aP)                                                      \
      aP += TBK; bP += TBK;                                                        \
    }                                                                              \
    SB0;                                                                           \
    __builtin_amdgcn_s_setprio(1);                                                 \
    _Pragma("unroll") for (int s = 0; s < 2; ++s)                                  \
      _Pragma("unroll") for (int mi = 0; mi < 4; ++mi)                             \
        _Pragma("unroll") for (int qn = 0; qn < 2; ++qn)                           \
          _Pragma("unroll") for (int ni = 0; ni < 2; ++ni)                         \
            acc[1][qn][mi][ni] = __builtin_amdgcn_mfma_f32_16x16x32_bf16(          \
                a1[mi][s], bfr[qn][ni][s], acc[1][qn][mi][ni], 0, 0, 0);           \
    __builtin_amdgcn_s_setprio(0);                                                 \
    SB0;                                                                           \
    if (!LAST) { VMW(2); SBAR; }                                                   \
  }

__global__ __launch_bounds__(512, 2) void k_gemm8(const bf16* __restrict__ A,
                                                  const bf16* __restrict__ Bw,
                                                  const float* __restrict__ bias,
                                                  const float* __restrict__ residual,
                                                  float* __restrict__ out) {
  __shared__ __align__(16) bf16 As[2][256][TBK];   // 64 KB
  __shared__ __align__(16) bf16 Bs[2][256][TBK];   // 64 KB

  const int tid  = threadIdx.x;
  const int lane = tid & 63;
  const int wave = tid >> 6;          // 0..7
  const int wm = wave >> 2;           // 0..1
  const int wn = wave & 3;            // 0..3
  const int quad = lane >> 4, l15 = lane & 15;

  // bijective XCD swizzle (512 % 8 == 0): each XCD owns 2 bn columns (4 MiB
  // wt panel in its L2); consecutive locals pair over bn to share A-tiles.
  const int wgid = (blockIdx.x & 7) * 64 + (blockIdx.x >> 3);
  const int bn = (wgid >> 6) * 2 + (wgid & 1);
  const int bm = (wgid & 63) >> 1;
  const int m0 = bm * 256, n0 = bn * 256;

  // staging: lane -> row (l>>3), phys chunk l&7; source fetches logical
  // chunk (l&7)^(row&7) so LDS holds the XOR swizzle.
  const int st_r = lane >> 3;
  const int st_c = ((lane & 7) ^ st_r) * 8;

  // fragment read: logical chunk (s*4+quad) of row r -> phys ^= (r&7)
  const int rdc[2] = { ((quad)     ^ (l15 & 7)) * 8,
                       ((4 + quad) ^ (l15 & 7)) * 8 };

  floatx4 acc[2][2][4][2] = {};   // [qm][qn][mi][ni]

  // per-thread stage pointers (row = base + wave*16 + st_r, at tile-0 k)
  const bf16* aP = A  + (size_t)(m0 + wave * 16 + st_r) * K_DIM + st_c;
  const bf16* bP = Bw + (size_t)(n0 + wave * 16 + st_r) * K_DIM + st_c;

  // ---- prologue: full tile 0 in issue order [Alo, Blo, Bhi, Ahi]
  STAGE_A(0, 0, aP)
  STAGE_B(0, 0, bP)
  STAGE_B(0, 1, bP)
  STAGE_A(0, 1, aP)
  aP += TBK; bP += TBK;
  VMW(2);                 // drain Alo,Blo,Bhi(0); leave Ahi(0) in flight
  SBAR;

#pragma unroll 1
  for (int t = 0; t < TNT - 2; t += 2) {
    TILE(0, true, false)
    TILE(1, true, false)
  }
  TILE(0, true, false)    // tile 62: stages tile 63
  TILE(1, false, true)    // tile 63: compute only

  // ---- epilogue: out = acc + bias + residual (C/D: col=l15, row=quad*4+r)
#pragma unroll
  for (int qn = 0; qn < 2; ++qn)
#pragma unroll
    for (int ni = 0; ni < 2; ++ni) {
      int col = n0 + qn * 128 + wn * 32 + ni * 16 + l15;
      float bv = bias[col];
#pragma unroll
      for (int qm = 0; qm < 2; ++qm)
#pragma unroll
        for (int mi = 0; mi < 4; ++mi) {
          int rbase = m0 + qm * 128 + wm * 64 + mi * 16 + quad * 4;
#pragma unroll
          for (int r = 0; r < 4; ++r) {
            size_t o = (size_t)(rbase + r) * N_DIM + col;
            out[o] = acc[qm][qn][mi][ni][r] + bv + residual[o];
          }
        }
    }
}

extern "C" void kernel_launch(void* const* d_in, const int* in_sizes, int n_in,
                              void* d_out, int out_size, void* d_ws, size_t ws_size,
                              hipStream_t stream) {
  const float* input    = (const float*)d_in[0];
  const float* residual = (const float*)d_in[1];
  const int*   qweight  = (const int*)d_in[2];
  const float* scales   = (const float*)d_in[3];
  const int*   qzeros   = (const int*)d_in[4];
  const float* bias     = (const float*)d_in[5];
  float* out = (float*)d_out;

  const size_t wt_bytes = (size_t)N_DIM * K_DIM * sizeof(bf16);   // 32 MiB
  const size_t a_bytes  = (size_t)M_DIM * K_DIM * sizeof(bf16);   // 64 MiB

  bf16* wt = (bf16*)d_ws;

  if (ws_size >= wt_bytes + a_bytes) {
    bf16* a_bf = (bf16*)((char*)d_ws + wt_bytes);
    k_prep<<<64 * 128 + (M_DIM * K_DIM / 8) / 256, 256, 0, stream>>>(
        qweight, scales, qzeros, wt, input, a_bf);
    k_gemm8<<<(M_DIM / 256) * (N_DIM / 256), 512, 0, stream>>>(
        a_bf, wt, bias, residual, out);
  } else {
    k_prep<<<64 * 128, 256, 0, stream>>>(qweight, scales, qzeros, wt, input, nullptr);
    k_gemm<false><<<NBLK_M * NBLK_N, 256, 0, stream>>>(input, wt, bias, residual, out);
  }
}

// Round 3
// 588.177 us; speedup vs baseline: 1.0982x; 1.0171x over previous
//
#include <hip/hip_runtime.h>
#include <hip/hip_bf16.h>
#include <stdint.h>

using bf16 = __hip_bfloat16;
typedef __attribute__((ext_vector_type(8))) short short8;
typedef __attribute__((ext_vector_type(4))) float floatx4;

#define DEVINL __device__ __forceinline__

constexpr int K_DIM = 4096;
constexpr int N_DIM = 4096;
constexpr int M_DIM = 8192;   // B * S = 2 * 4096

// ---- async global->LDS, 16B per lane; LDS dest = wave-uniform base + lane*16
DEVINL void gload_lds16(const void* g, void* l) {
  __builtin_amdgcn_global_load_lds((const __attribute__((address_space(1))) void*)g,
                                   (__attribute__((address_space(3))) void*)l,
                                   16, 0, 0);
}

// =====================================================================
// Prep: 2048 blocks, grid-strided (G11: tiny-block dispatch overhead).
// blocks [0,1024): GPTQ int4 dequant -> bf16 W^T [N][K], 8 jobs each.
// blocks [1024,2048): A fp32 -> bf16, 16 jobs each.
// =====================================================================
__global__ __launch_bounds__(256) void k_prep(const int* __restrict__ qw,
                                              const float* __restrict__ scales,
                                              const int* __restrict__ qz,
                                              bf16* __restrict__ wt,
                                              const float* __restrict__ a,
                                              bf16* __restrict__ ao) {
  if (blockIdx.x < 1024) {
    __shared__ __align__(16) uint4 lds[32 * 8];
    const int t = threadIdx.x;
    const int n_l = t & 31, kp_l = t >> 5;
    const int n_o = t >> 3, kp_o = t & 7;
#pragma unroll 1
    for (int j = 0; j < 8; ++j) {
      const int jb = blockIdx.x + j * 1024;        // 0..8191
      const int kp0 = (jb & 63) * 8;
      const int n0  = (jb >> 6) * 32;
      const int n = n0 + n_l, kp = kp0 + kp_l;
      int q = qw[kp * N_DIM + n];                  // coalesced (n fastest)
      int g = kp0 >> 4;                            // uniform (kp0 % 8 == 0)
      float s = scales[g * N_DIM + n];
      int zword = qz[g * (N_DIM / 8) + (n >> 3)];
      float z = (float)((zword >> ((n & 7) * 4)) & 0xF);
      float nzs = -z * s;
      bf16 h[8];
#pragma unroll
      for (int i = 0; i < 8; ++i)
        h[i] = __float2bfloat16(fmaf((float)((q >> (4 * i)) & 0xF), s, nzs));
      lds[n_l * 8 + (kp_l ^ (n_l & 7))] = *(const uint4*)h;
      __syncthreads();
      uint4 v = lds[n_o * 8 + (kp_o ^ (n_o & 7))];
      ((uint4*)wt)[(size_t)(n0 + n_o) * (K_DIM / 8) + kp0 + kp_o] = v;
      __syncthreads();
    }
  } else if (ao) {
    const int base = (blockIdx.x - 1024) * 256 + threadIdx.x;   // 0..262143
    const float4* a4 = (const float4*)a;
#pragma unroll 1
    for (int j = 0; j < 16; ++j) {
      int t = base + j * 262144;                   // coalesced per iteration
      float4 v0 = a4[2 * t], v1 = a4[2 * t + 1];
      bf16 h[8];
      h[0] = __float2bfloat16(v0.x); h[1] = __float2bfloat16(v0.y);
      h[2] = __float2bfloat16(v0.z); h[3] = __float2bfloat16(v0.w);
      h[4] = __float2bfloat16(v1.x); h[5] = __float2bfloat16(v1.y);
      h[6] = __float2bfloat16(v1.z); h[7] = __float2bfloat16(v1.w);
      ((uint4*)ao)[t] = *(const uint4*)h;
    }
  }
}

// =====================================================================
// Fallback GEMM (verified 128x128, fp32-A path) — small-workspace only.
// =====================================================================
constexpr int BM = 128, BN = 128, BK = 64;
constexpr int NBLK_N = N_DIM / BN;
constexpr int NBLK_M = M_DIM / BM;

template <bool A_IS_BF16>
__global__ __launch_bounds__(256, 2) void k_gemm(const void* __restrict__ a_ptr,
                                                 const bf16* __restrict__ wt,
                                                 const float* __restrict__ bias,
                                                 const float* __restrict__ residual,
                                                 float* __restrict__ out) {
  __shared__ __align__(16) bf16 As[BM * BK];
  __shared__ __align__(16) bf16 Bs[BN * BK];

  const int tid  = threadIdx.x;
  const int lane = tid & 63;
  const int wave = tid >> 6;
  const int wr = wave >> 1, wc = wave & 1;
  const int quad = lane >> 4, lq = lane & 15;

  const int xcd = blockIdx.x & 7;
  const int idx = blockIdx.x >> 3;
  const int bn = xcd * 4 + (idx & 3);
  const int bm = idx >> 2;
  const int m0 = bm * BM, n0 = bn * BN;

  floatx4 acc[4][4] = {};

  const int st_r8 = lane >> 3;
  const int st_ce = ((lane & 7) ^ (st_r8 & 7)) * 8;
  const int rd_x = lq & 7;

  const bf16*  a_bf = (const bf16*)a_ptr;
  const float* a_f  = (const float*)a_ptr;

  for (int k0 = 0; k0 < K_DIM; k0 += BK) {
    __syncthreads();
#pragma unroll
    for (int j = 0; j < 4; ++j) {
      int g = wave + j * 4;
      const bf16* gp = wt + (size_t)(n0 + g * 8 + st_r8) * K_DIM + k0 + st_ce;
      gload_lds16(gp, &Bs[g * 512]);
    }
    if (A_IS_BF16) {
#pragma unroll
      for (int j = 0; j < 4; ++j) {
        int g = wave + j * 4;
        const bf16* gp = a_bf + (size_t)(m0 + g * 8 + st_r8) * K_DIM + k0 + st_ce;
        gload_lds16(gp, &As[g * 512]);
      }
    } else {
      int row = tid >> 1, half = tid & 1;
      int rx = row & 7;
      const float* srcf = a_f + (size_t)(m0 + row) * K_DIM + k0 + half * 32;
#pragma unroll
      for (int cc = 0; cc < 4; ++cc) {
        int logc = half * 4 + cc;
        float4 v0 = ((const float4*)srcf)[cc * 2];
        float4 v1 = ((const float4*)srcf)[cc * 2 + 1];
        bf16 h[8];
        h[0] = __float2bfloat16(v0.x); h[1] = __float2bfloat16(v0.y);
        h[2] = __float2bfloat16(v0.z); h[3] = __float2bfloat16(v0.w);
        h[4] = __float2bfloat16(v1.x); h[5] = __float2bfloat16(v1.y);
        h[6] = __float2bfloat16(v1.z); h[7] = __float2bfloat16(v1.w);
        *(uint4*)&As[row * BK + ((logc ^ rx) * 8)] = *(const uint4*)h;
      }
    }
    __syncthreads();

#pragma unroll
    for (int s = 0; s < 2; ++s) {
      short8 afr[4], bfr[4];
#pragma unroll
      for (int mi = 0; mi < 4; ++mi)
        afr[mi] = *(const short8*)&As[(wr * 64 + mi * 16 + lq) * BK +
                                      (((s * 4 + quad) ^ rd_x) * 8)];
#pragma unroll
      for (int ni = 0; ni < 4; ++ni)
        bfr[ni] = *(const short8*)&Bs[(wc * 64 + ni * 16 + lq) * BK +
                                      (((s * 4 + quad) ^ rd_x) * 8)];
#pragma unroll
      for (int mi = 0; mi < 4; ++mi)
#pragma unroll
        for (int ni = 0; ni < 4; ++ni)
          acc[mi][ni] = __builtin_amdgcn_mfma_f32_16x16x32_bf16(afr[mi], bfr[ni],
                                                                acc[mi][ni], 0, 0, 0);
    }
  }

#pragma unroll
  for (int ni = 0; ni < 4; ++ni) {
    int col = n0 + wc * 64 + ni * 16 + lq;
    float bv = bias[col];
#pragma unroll
    for (int mi = 0; mi < 4; ++mi) {
      int rbase = m0 + wr * 64 + mi * 16 + quad * 4;
#pragma unroll
      for (int r = 0; r < 4; ++r) {
        size_t idxo = (size_t)(rbase + r) * N_DIM + col;
        out[idxo] = acc[mi][ni][r] + bv + residual[idxo];
      }
    }
  }
}

// =====================================================================
// Main GEMM: faithful m201 8-phase template. 256x256, BK=64, 8 waves
// (2Mx4N). LDS = [buf][half][128][64] per operand (128 KiB total).
// Per K-tile: 4 phases, each = {ds_read subtile; stage 1 half-tile;
// [lgkmcnt(8) if 12 reads]; s_barrier; lgkmcnt(0); setprio(1); 16 MFMA;
// setprio(0); s_barrier}.  Phase q-order (qm,qn)=(0,0),(0,1),(1,0),(1,1);
// A-subtile reloaded phases 1,3 (8 reads), B-subtile every phase (4).
//
// Stage rotation (race-free by barrier structure):
//   p1: B-lo(t+1)->buf^1   p2: B-hi(t+1)->buf^1     (buf^1 not read by t)
//   p3: A-lo(t+2)->buf     (A-lo(t) reads drained at p1's lgkmcnt(0))
//   p4: A-hi(t+2)->buf     (A-hi(t) reads drained at p3's lgkmcnt(0))
// Boundary (end p4): vmcnt(4) drains everything tile t+1 needs, leaves
// A(t+2)'s 4 loads in flight with a full tile (~3300 cyc) of cover.
// Each wave reads ONE B-half (wn>>1): cols = (wn>>1)*128+(wn&1)*64+qn*32.
// =====================================================================
constexpr int TBK = 64;
constexpr int TNT = K_DIM / TBK;   // 64

#define SB0   __builtin_amdgcn_sched_barrier(0)
#define SBAR  __builtin_amdgcn_s_barrier()
#define PRIO1 __builtin_amdgcn_s_setprio(1)
#define PRIO0 __builtin_amdgcn_s_setprio(0)
#define LGKM0 asm volatile("s_waitcnt lgkmcnt(0)" ::: "memory")
#define LGKM8 asm volatile("s_waitcnt lgkmcnt(8)" ::: "memory")
#define VMW4  asm volatile("s_waitcnt vmcnt(4)" ::: "memory")
#define VMW0  asm volatile("s_waitcnt vmcnt(0)" ::: "memory")

#define ST_A(b, h, kt) {                                                      \
    const bf16* g_ = A + (size_t)(m0 + (h) * 128 + wave * 16 + st_r) * K_DIM  \
                       + (kt) * TBK + st_c;                                   \
    gload_lds16(g_,             &As[b][h][wave * 16    ][0]);                 \
    gload_lds16(g_ + 8 * K_DIM, &As[b][h][wave * 16 + 8][0]);                 \
  }

#define ST_B(b, h, kt) {                                                      \
    const bf16* g_ = Bw + (size_t)(n0 + (h) * 128 + wave * 16 + st_r) * K_DIM \
                       + (kt) * TBK + st_c;                                   \
    gload_lds16(g_,             &Bs[b][h][wave * 16    ][0]);                 \
    gload_lds16(g_ + 8 * K_DIM, &Bs[b][h][wave * 16 + 8][0]);                 \
  }

#define RD_A(c, qm)                                                           \
  _Pragma("unroll") for (int mi = 0; mi < 4; ++mi)                            \
    _Pragma("unroll") for (int s = 0; s < 2; ++s)                             \
      aS[mi][s] = *(const short8*)&As[c][qm][wm * 64 + mi * 16 + l15][rdc[s]];

#define RD_B(c, qn)                                                           \
  _Pragma("unroll") for (int ni = 0; ni < 2; ++ni)                            \
    _Pragma("unroll") for (int s = 0; s < 2; ++s)                             \
      bS[ni][s] = *(const short8*)                                            \
          &Bs[c][bh][br0 + (qn) * 32 + ni * 16 + l15][rdc[s]];

#define MFMA16(qm, qn)                                                        \
  _Pragma("unroll") for (int s = 0; s < 2; ++s)                               \
    _Pragma("unroll") for (int mi = 0; mi < 4; ++mi)                          \
      _Pragma("unroll") for (int ni = 0; ni < 2; ++ni)                        \
        acc[qm][qn][mi][ni] = __builtin_amdgcn_mfma_f32_16x16x32_bf16(        \
            aS[mi][s], bS[ni][s], acc[qm][qn][mi][ni], 0, 0, 0);

#define TILE(c, t, STB, STA, WMACRO)                                          \
  {                                                                           \
    short8 aS[4][2], bS[2][2];                                                \
    /* p1: q=(0,0) */                                                         \
    RD_A(c, 0) RD_B(c, 0)                                                     \
    if (STB) ST_B((c) ^ 1, 0, (t) + 1)                                        \
    SB0; LGKM8; SBAR; LGKM0; SB0;                                             \
    PRIO1; MFMA16(0, 0) PRIO0; SB0; SBAR;                                     \
    /* p2: q=(0,1), A held in regs */                                         \
    RD_B(c, 1)                                                                \
    if (STB) ST_B((c) ^ 1, 1, (t) + 1)                                        \
    SB0; SBAR; LGKM0; SB0;                                                    \
    PRIO1; MFMA16(0, 1) PRIO0; SB0; SBAR;                                     \
    /* p3: q=(1,0) */                                                         \
    RD_A(c, 1) RD_B(c, 0)                                                     \
    if (STA) ST_A(c, 0, (t) + 2)                                              \
    SB0; LGKM8; SBAR; LGKM0; SB0;                                             \
    PRIO1; MFMA16(1, 0) PRIO0; SB0; SBAR;                                     \
    /* p4: q=(1,1) */                                                         \
    RD_B(c, 1)                                                                \
    if (STA) ST_A(c, 1, (t) + 2)                                              \
    SB0; SBAR; LGKM0; SB0;                                                    \
    PRIO1; MFMA16(1, 1) PRIO0; SB0; WMACRO; SBAR;                             \
  }

__global__ __launch_bounds__(512, 2) void k_gemm8(const bf16* __restrict__ A,
                                                  const bf16* __restrict__ Bw,
                                                  const float* __restrict__ bias,
                                                  const float* __restrict__ residual,
                                                  float* __restrict__ out) {
  __shared__ __align__(16) bf16 As[2][2][128][TBK];   // 64 KB
  __shared__ __align__(16) bf16 Bs[2][2][128][TBK];   // 64 KB

  const int tid  = threadIdx.x;
  const int lane = tid & 63;
  const int wave = tid >> 6;          // 0..7
  const int wm = wave >> 2;           // 0..1
  const int wn = wave & 3;            // 0..3
  const int quad = lane >> 4, l15 = lane & 15;
  const int bh  = wn >> 1;            // this wave's B half
  const int br0 = (wn & 1) * 64;      // row base within half

  // bijective XCD swizzle (512 % 8 == 0): each XCD owns 2 bn columns (4 MiB
  // wt panel in its L2); consecutive locals pair over bn to share A-tiles.
  const int wgid = (blockIdx.x & 7) * 64 + (blockIdx.x >> 3);
  const int bn = (wgid >> 6) * 2 + (wgid & 1);
  const int bm = (wgid & 63) >> 1;
  const int m0 = bm * 256, n0 = bn * 256;

  // staging: lane -> row (l>>3), phys chunk l&7; source fetches logical
  // chunk (l&7)^(row&7) so LDS holds the XOR swizzle.
  const int st_r = lane >> 3;
  const int st_c = ((lane & 7) ^ st_r) * 8;

  // fragment read: logical chunk (s*4+quad) of row r -> phys ^= (r&7)
  const int rdc[2] = { ((quad)     ^ (l15 & 7)) * 8,
                       ((4 + quad) ^ (l15 & 7)) * 8 };

  floatx4 acc[2][2][4][2] = {};   // [qm][qn][mi][ni]

  // ---- prologue: tile0 all halves + tile1 A-halves; order matches steady
  // vmcnt counting: [Blo0,Bhi0,Alo0,Ahi0, Alo1,Ahi1] -> vmcnt(4) leaves A(1).
  ST_B(0, 0, 0) ST_B(0, 1, 0)
  ST_A(0, 0, 0) ST_A(0, 1, 0)
  ST_A(1, 0, 1) ST_A(1, 1, 1)
  VMW4; SBAR;

#pragma unroll 1
  for (int t = 0; t < TNT - 2; t += 2) {
    TILE(0, t,     1, 1, VMW4)
    TILE(1, t + 1, 1, 1, VMW4)
  }
  TILE(0, TNT - 2, 1, 0, VMW0)   // tile 62: stage B(63); drain all
  TILE(1, TNT - 1, 0, 0, )       // tile 63: compute only

  // ---- epilogue: out = acc + bias + residual (C/D: col=l15, row=quad*4+r)
#pragma unroll
  for (int qn = 0; qn < 2; ++qn)
#pragma unroll
    for (int ni = 0; ni < 2; ++ni) {
      int col = n0 + bh * 128 + br0 + qn * 32 + ni * 16 + l15;
      float bv = bias[col];
#pragma unroll
      for (int qm = 0; qm < 2; ++qm)
#pragma unroll
        for (int mi = 0; mi < 4; ++mi) {
          int rbase = m0 + qm * 128 + wm * 64 + mi * 16 + quad * 4;
#pragma unroll
          for (int r = 0; r < 4; ++r) {
            size_t o = (size_t)(rbase + r) * N_DIM + col;
            out[o] = acc[qm][qn][mi][ni][r] + bv + residual[o];
          }
        }
    }
}

extern "C" void kernel_launch(void* const* d_in, const int* in_sizes, int n_in,
                              void* d_out, int out_size, void* d_ws, size_t ws_size,
                              hipStream_t stream) {
  const float* input    = (const float*)d_in[0];
  const float* residual = (const float*)d_in[1];
  const int*   qweight  = (const int*)d_in[2];
  const float* scales   = (const float*)d_in[3];
  const int*   qzeros   = (const int*)d_in[4];
  const float* bias     = (const float*)d_in[5];
  float* out = (float*)d_out;

  const size_t wt_bytes = (size_t)N_DIM * K_DIM * sizeof(bf16);   // 32 MiB
  const size_t a_bytes  = (size_t)M_DIM * K_DIM * sizeof(bf16);   // 64 MiB

  bf16* wt = (bf16*)d_ws;

  if (ws_size >= wt_bytes + a_bytes) {
    bf16* a_bf = (bf16*)((char*)d_ws + wt_bytes);
    k_prep<<<2048, 256, 0, stream>>>(qweight, scales, qzeros, wt, input, a_bf);
    k_gemm8<<<(M_DIM / 256) * (N_DIM / 256), 512, 0, stream>>>(
        a_bf, wt, bias, residual, out);
  } else {
    k_prep<<<1024, 256, 0, stream>>>(qweight, scales, qzeros, wt, input, nullptr);
    k_gemm<false><<<NBLK_M * NBLK_N, 256, 0, stream>>>(input, wt, bias, residual, out);
  }
}